// Round 10
// baseline (88958.752 us; speedup 1.0000x reference)
//
#include <hip/hip_runtime.h>
#include <hip/hip_fp16.h>

#define T_STEPS 65536
#define IN_DIM 5
#define H1 26
#define H2 121

__device__ __forceinline__ float fsig(float x) {
    float e = __builtin_amdgcn_exp2f(-1.44269504f * x);
    return __builtin_amdgcn_rcpf(1.0f + e);
}
__device__ __forceinline__ float ftanh(float x) {
    float e = __builtin_amdgcn_exp2f(2.88539008f * x);
    return 1.0f - 2.0f * __builtin_amdgcn_rcpf(e + 1.0f);
}
__device__ __forceinline__ uint32_t pk2h(float lo, float hi) {
    unsigned short ul = __half_as_ushort(__float2half(lo));
    unsigned short uh = __half_as_ushort(__float2half(hi));
    return ((uint32_t)uh << 16) | ul;
}

// mixed-precision FMA: acc(f32) += f16(a) * f16(b); lo/hi half selected
// (R8's exact arithmetic — kept bit-identical; dot2/stagger re-rolled the
//  fp16 error-envelope dice and failed in R9)
#define MIX_LO(acc, a, b) asm("v_fma_mix_f32 %0, %1, %2, %0 op_sel:[0,0,0] op_sel_hi:[1,1,0]" : "+v"(acc) : "v"(a), "v"(b));
#define MIX_HI(acc, a, b) asm("v_fma_mix_f32 %0, %1, %2, %0 op_sel:[1,1,0] op_sel_hi:[1,1,0]" : "+v"(acc) : "v"(a), "v"(b));
#define PIN(a) asm volatile("" : "+v"(a));
#define SB() __builtin_amdgcn_sched_barrier(0)

#define FORW61(F) F(0) F(1) F(2) F(3) F(4) F(5) F(6) F(7) F(8) F(9) F(10) F(11) F(12) F(13) F(14) F(15) \
 F(16) F(17) F(18) F(19) F(20) F(21) F(22) F(23) F(24) F(25) F(26) F(27) F(28) F(29) F(30) F(31) \
 F(32) F(33) F(34) F(35) F(36) F(37) F(38) F(39) F(40) F(41) F(42) F(43) F(44) F(45) F(46) F(47) \
 F(48) F(49) F(50) F(51) F(52) F(53) F(54) F(55) F(56) F(57) F(58) F(59) F(60)
#define FOR13(F) F(0) F(1) F(2) F(3) F(4) F(5) F(6) F(7) F(8) F(9) F(10) F(11) F(12)

// 512 threads = 8 waves = 2 waves/SIMD. R8 skeleton, R8 math (bit-identical
// recurrence). Scheduling-only changes: gate-interleaved g2w (b128 act read),
// 3-level y-reduce + 16 LDS partials summed by tid 510 in region1.
// tid 0..483  : gates2 row r=tid (region1); tid<121 also act role (region2)
// tid 484..509: LSTM1 unit l=tid-484 (region2; x-prefetch in region1)
// tid 510     : y partial-sum + store of step t-1 (region1)
__global__ __attribute__((amdgpu_flat_work_group_size(512, 512)))
__attribute__((amdgpu_waves_per_eu(2, 2)))
void lstm_seq_kernel(
    const float* __restrict__ x,
    const float* __restrict__ W_ih1, const float* __restrict__ W_hh1,
    const float* __restrict__ b_ih1, const float* __restrict__ b_hh1,
    const float* __restrict__ W_ih2, const float* __restrict__ W_hh2,
    const float* __restrict__ b_ih2, const float* __restrict__ b_hh2,
    const float* __restrict__ W_lin, const float* __restrict__ b_lin,
    const float* __restrict__ h1_0, const float* __restrict__ c1_0,
    const float* __restrict__ h2_0, const float* __restrict__ c2_0,
    float* __restrict__ out)
{
    __shared__ __align__(16) unsigned short h2f16[128];  // h2(t) fp16, pad 121..127 = 0
    __shared__ __align__(16) unsigned short h1f16[32];   // h1(t) fp16, pad 26..31 = 0
    __shared__ __align__(16) float g2w[484];             // gate-interleaved [j*4+g]
    __shared__ __align__(16) float yp8[16];              // 8-lane partial sums

    const int tid = threadIdx.x;
    const bool is_g2 = (tid < 484);
    const int  l     = tid - 484;
    const bool is_l1 = ((unsigned)l < 26u);
    int gg_ = 0, jj_ = 0;
    if (is_g2) { gg_ = tid / 121; jj_ = tid - gg_ * 121; }
    const int goff = jj_ * 4 + gg_;

    // ---------------- packed-f16 weight registers ----------------
#define DECW(i) uint32_t w##i = 0;
    FORW61(DECW)
#define DECU(i) uint32_t u##i = 0;
    FOR13(DECU)
#define DECK(i) uint32_t k0_##i = 0, k1_##i = 0, k2_##i = 0, k3_##i = 0;
    FOR13(DECK)
    uint32_t i0_0=0,i0_1=0,i0_2=0, i1_0=0,i1_1=0,i1_2=0;
    uint32_t i2_0=0,i2_1=0,i2_2=0, i3_0=0,i3_1=0,i3_2=0;
    float bias = 0.0f, c2 = 0.0f, wlin = 0.0f;
    float bb0=0, bb1=0, bb2=0, bb3=0, c1 = 0.0f;
    uint32_t px01 = 0, px23 = 0, px4r = 0;

    if (is_g2) {
        const float* wp = W_hh2 + tid * H2;
#define PKW(i) w##i = pk2h(wp[2*(i)], wp[2*(i)+1]);
        PKW(0) PKW(1) PKW(2) PKW(3) PKW(4) PKW(5) PKW(6) PKW(7) PKW(8) PKW(9)
        PKW(10) PKW(11) PKW(12) PKW(13) PKW(14) PKW(15) PKW(16) PKW(17) PKW(18) PKW(19)
        PKW(20) PKW(21) PKW(22) PKW(23) PKW(24) PKW(25) PKW(26) PKW(27) PKW(28) PKW(29)
        PKW(30) PKW(31) PKW(32) PKW(33) PKW(34) PKW(35) PKW(36) PKW(37) PKW(38) PKW(39)
        PKW(40) PKW(41) PKW(42) PKW(43) PKW(44) PKW(45) PKW(46) PKW(47) PKW(48) PKW(49)
        PKW(50) PKW(51) PKW(52) PKW(53) PKW(54) PKW(55) PKW(56) PKW(57) PKW(58) PKW(59)
        w60 = pk2h(wp[120], 0.0f);
        const float* up = W_ih2 + tid * H1;
#define PKU(i) u##i = pk2h(up[2*(i)], up[2*(i)+1]);
        FOR13(PKU)
        bias = b_ih2[tid] + b_hh2[tid];
#define PINW(i) PIN(w##i)
        FORW61(PINW)
#define PINU(i) PIN(u##i)
        FOR13(PINU)
        PIN(bias)
    } else if (is_l1) {
        const float* p0 = W_hh1 + (0 * 26 + l) * H1;
        const float* p1 = W_hh1 + (1 * 26 + l) * H1;
        const float* p2 = W_hh1 + (2 * 26 + l) * H1;
        const float* p3 = W_hh1 + (3 * 26 + l) * H1;
#define PKK(i) k0_##i = pk2h(p0[2*(i)], p0[2*(i)+1]); k1_##i = pk2h(p1[2*(i)], p1[2*(i)+1]); \
               k2_##i = pk2h(p2[2*(i)], p2[2*(i)+1]); k3_##i = pk2h(p3[2*(i)], p3[2*(i)+1]);
        FOR13(PKK)
        const float* q0 = W_ih1 + (0 * 26 + l) * IN_DIM;
        const float* q1 = W_ih1 + (1 * 26 + l) * IN_DIM;
        const float* q2 = W_ih1 + (2 * 26 + l) * IN_DIM;
        const float* q3 = W_ih1 + (3 * 26 + l) * IN_DIM;
        i0_0 = pk2h(q0[0], q0[1]); i0_1 = pk2h(q0[2], q0[3]); i0_2 = pk2h(q0[4], 0.0f);
        i1_0 = pk2h(q1[0], q1[1]); i1_1 = pk2h(q1[2], q1[3]); i1_2 = pk2h(q1[4], 0.0f);
        i2_0 = pk2h(q2[0], q2[1]); i2_1 = pk2h(q2[2], q2[3]); i2_2 = pk2h(q2[4], 0.0f);
        i3_0 = pk2h(q3[0], q3[1]); i3_1 = pk2h(q3[2], q3[3]); i3_2 = pk2h(q3[4], 0.0f);
        bb0 = b_ih1[l]      + b_hh1[l];
        bb1 = b_ih1[26 + l] + b_hh1[26 + l];
        bb2 = b_ih1[52 + l] + b_hh1[52 + l];
        bb3 = b_ih1[78 + l] + b_hh1[78 + l];
        c1  = c1_0[l];
        px01 = pk2h(x[0], x[1]); px23 = pk2h(x[2], x[3]); px4r = pk2h(x[4], 0.0f);
#define PINK(i) PIN(k0_##i) PIN(k1_##i) PIN(k2_##i) PIN(k3_##i)
        FOR13(PINK)
        PIN(i0_0) PIN(i0_1) PIN(i0_2) PIN(i1_0) PIN(i1_1) PIN(i1_2)
        PIN(i2_0) PIN(i2_1) PIN(i2_2) PIN(i3_0) PIN(i3_1) PIN(i3_2)
        PIN(bb0) PIN(bb1) PIN(bb2) PIN(bb3)
    }
    if (tid < H2) { c2 = c2_0[tid]; wlin = W_lin[tid]; PIN(c2) PIN(wlin) }
    const float blin = b_lin[0];

    if (tid < 32)  h1f16[tid] = (tid < H1) ? __half_as_ushort(__float2half(h1_0[tid])) : (unsigned short)0;
    if (tid >= 32 && tid < 160) {
        int j = tid - 32;
        h2f16[j] = (j < H2) ? __half_as_ushort(__float2half(h2_0[j])) : (unsigned short)0;
    }
    __syncthreads();

    // LSTM1 step macro (R8-identical): gates from h1f16 broadcast + packed x
#define L1_STEP() { \
        const uint4* Hc = (const uint4*)h1f16; \
        uint4 hc0 = Hc[0], hc1 = Hc[1], hc2 = Hc[2], hc3 = Hc[3]; \
        float A0 = bb0, A1 = bb1, A2 = bb2, A3 = bb3; \
        MIX_LO(A0, i0_0, px01) MIX_HI(A0, i0_0, px01) MIX_LO(A0, i0_1, px23) MIX_HI(A0, i0_1, px23) MIX_LO(A0, i0_2, px4r) \
        MIX_LO(A1, i1_0, px01) MIX_HI(A1, i1_0, px01) MIX_LO(A1, i1_1, px23) MIX_HI(A1, i1_1, px23) MIX_LO(A1, i1_2, px4r) \
        MIX_LO(A2, i2_0, px01) MIX_HI(A2, i2_0, px01) MIX_LO(A2, i2_1, px23) MIX_HI(A2, i2_1, px23) MIX_LO(A2, i2_2, px4r) \
        MIX_LO(A3, i3_0, px01) MIX_HI(A3, i3_0, px01) MIX_LO(A3, i3_1, px23) MIX_HI(A3, i3_1, px23) MIX_LO(A3, i3_2, px4r) \
        GATE(A0, k0_) GATE(A1, k1_) GATE(A2, k2_) GATE(A3, k3_) \
        c1 = fsig(A1) * c1 + fsig(A0) * ftanh(A2); \
        h1f16[l] = __half_as_ushort(__float2half(fsig(A3) * ftanh(c1))); }
#define GATE(A, K) \
        MIX_LO(A, K##0, hc0.x) MIX_HI(A, K##0, hc0.x) MIX_LO(A, K##1, hc0.y) MIX_HI(A, K##1, hc0.y) \
        MIX_LO(A, K##2, hc0.z) MIX_HI(A, K##2, hc0.z) MIX_LO(A, K##3, hc0.w) MIX_HI(A, K##3, hc0.w) \
        MIX_LO(A, K##4, hc1.x) MIX_HI(A, K##4, hc1.x) MIX_LO(A, K##5, hc1.y) MIX_HI(A, K##5, hc1.y) \
        MIX_LO(A, K##6, hc1.z) MIX_HI(A, K##6, hc1.z) MIX_LO(A, K##7, hc1.w) MIX_HI(A, K##7, hc1.w) \
        MIX_LO(A, K##8, hc2.x) MIX_HI(A, K##8, hc2.x) MIX_LO(A, K##9, hc2.y) MIX_HI(A, K##9, hc2.y) \
        MIX_LO(A, K##10, hc2.z) MIX_HI(A, K##10, hc2.z) MIX_LO(A, K##11, hc2.w) MIX_HI(A, K##11, hc2.w) \
        MIX_LO(A, K##12, hc3.x) MIX_HI(A, K##12, hc3.x)

    // prologue: h1(0) from x(0), h1_0, c1_0
    if (is_l1) { L1_STEP() }
    __syncthreads();

    for (int t = 0; t < T_STEPS; ++t) {
        // -------- Region 1: gates2 = W_hh2@h2(t-1) + W_ih2@h1(t) + b --------
        if (is_g2) {
            const uint4* Hh = (const uint4*)h2f16;
            const uint4* Hl = (const uint4*)h1f16;
            float a0 = bias, a1 = 0.0f, a2 = 0.0f, a3 = 0.0f;
            uint4 h;
#define CH(WA, WB, WC, WD) \
            MIX_LO(a0, WA, h.x) MIX_HI(a1, WA, h.x) MIX_LO(a2, WB, h.y) MIX_HI(a3, WB, h.y) \
            MIX_LO(a0, WC, h.z) MIX_HI(a1, WC, h.z) MIX_LO(a2, WD, h.w) MIX_HI(a3, WD, h.w)
            h = Hh[0];  CH(w0,  w1,  w2,  w3)
            h = Hh[1];  CH(w4,  w5,  w6,  w7)
            h = Hh[2];  CH(w8,  w9,  w10, w11)
            h = Hh[3];  CH(w12, w13, w14, w15)
            SB();
            h = Hh[4];  CH(w16, w17, w18, w19)
            h = Hh[5];  CH(w20, w21, w22, w23)
            h = Hh[6];  CH(w24, w25, w26, w27)
            h = Hh[7];  CH(w28, w29, w30, w31)
            SB();
            h = Hh[8];  CH(w32, w33, w34, w35)
            h = Hh[9];  CH(w36, w37, w38, w39)
            h = Hh[10]; CH(w40, w41, w42, w43)
            h = Hh[11]; CH(w44, w45, w46, w47)
            SB();
            h = Hh[12]; CH(w48, w49, w50, w51)
            h = Hh[13]; CH(w52, w53, w54, w55)
            h = Hh[14]; CH(w56, w57, w58, w59)
            h = Hh[15]; MIX_LO(a0, w60, h.x) MIX_HI(a1, w60, h.x)
            h = Hl[0];  CH(u0,  u1,  u2,  u3)
            h = Hl[1];  CH(u4,  u5,  u6,  u7)
            h = Hl[2];  CH(u8,  u9,  u10, u11)
            h = Hl[3];  MIX_LO(a0, u12, h.x) MIX_HI(a1, u12, h.x)
            g2w[goff] = (a0 + a1) + (a2 + a3);
        } else if (is_l1) {
            int tn = t + 1; if (tn >= T_STEPS) tn = T_STEPS - 1;
            const float* xp = x + tn * IN_DIM;
            px01 = pk2h(xp[0], xp[1]); px23 = pk2h(xp[2], xp[3]); px4r = pk2h(xp[4], 0.0f);
        } else if (tid == 510) {
            if (t > 0) {
                const float4* Y4 = (const float4*)yp8;
                float4 y0 = Y4[0], y1 = Y4[1], y2 = Y4[2], y3 = Y4[3];
                float s = ((y0.x + y0.y) + (y0.z + y0.w))
                        + ((y1.x + y1.y) + (y1.z + y1.w))
                        + ((y2.x + y2.y) + (y2.z + y2.w))
                        + ((y3.x + y3.y) + (y3.z + y3.w));
                out[t - 1] = s + blin;
            }
        }
        __syncthreads();   // B2: gates2 visible

        // -------- Region 2: h2/c2 act + y partials  ||  LSTM1 -> h1(t+1) --------
        if (tid < 128) {
            float p = 0.0f;
            if (tid < H2) {
                float4 G = reinterpret_cast<const float4*>(g2w)[tid];  // i,f,g,o
                c2 = fsig(G.y) * c2 + fsig(G.x) * ftanh(G.z);
                float h2n = fsig(G.w) * ftanh(c2);
                h2f16[tid] = __half_as_ushort(__float2half(h2n));
                p = h2n * wlin;
            }
            // 3-level butterfly within 8-lane groups; 16 partials to LDS
            p += __shfl_xor(p, 1);
            p += __shfl_xor(p, 2);
            p += __shfl_xor(p, 4);
            if ((tid & 7) == 0) yp8[tid >> 3] = p;
        } else if (is_l1) {
            L1_STEP()
        }
        __syncthreads();   // B3: h2(t), yp8, h1(t+1) visible
    }

    if (tid == 510) {
        const float4* Y4 = (const float4*)yp8;
        float4 y0 = Y4[0], y1 = Y4[1], y2 = Y4[2], y3 = Y4[3];
        float s = ((y0.x + y0.y) + (y0.z + y0.w))
                + ((y1.x + y1.y) + (y1.z + y1.w))
                + ((y2.x + y2.y) + (y2.z + y2.w))
                + ((y3.x + y3.y) + (y3.z + y3.w));
        out[T_STEPS - 1] = s + blin;
    }
}

extern "C" void kernel_launch(void* const* d_in, const int* in_sizes, int n_in,
                              void* d_out, int out_size, void* d_ws, size_t ws_size,
                              hipStream_t stream) {
    const float* x     = (const float*)d_in[0];
    const float* W_ih1 = (const float*)d_in[1];
    const float* W_hh1 = (const float*)d_in[2];
    const float* b_ih1 = (const float*)d_in[3];
    const float* b_hh1 = (const float*)d_in[4];
    const float* W_ih2 = (const float*)d_in[5];
    const float* W_hh2 = (const float*)d_in[6];
    const float* b_ih2 = (const float*)d_in[7];
    const float* b_hh2 = (const float*)d_in[8];
    const float* W_lin = (const float*)d_in[9];
    const float* b_lin = (const float*)d_in[10];
    const float* h1_0  = (const float*)d_in[11];
    const float* c1_0  = (const float*)d_in[12];
    const float* h2_0  = (const float*)d_in[13];
    const float* c2_0  = (const float*)d_in[14];
    float* out = (float*)d_out;

    hipLaunchKernelGGL(lstm_seq_kernel, dim3(1), dim3(512), 0, stream,
                       x, W_ih1, W_hh1, b_ih1, b_hh1,
                       W_ih2, W_hh2, b_ih2, b_hh2,
                       W_lin, b_lin, h1_0, c1_0, h2_0, c2_0, out);
}

// Round 11
// 87708.405 us; speedup vs baseline: 1.0143x; 1.0143x over previous
//
#include <hip/hip_runtime.h>
#include <hip/hip_fp16.h>

#define T_STEPS 65536
#define IN_DIM 5
#define H1 26
#define H2 121

__device__ __forceinline__ float fsig(float x) {
    float e = __builtin_amdgcn_exp2f(-1.44269504f * x);
    return __builtin_amdgcn_rcpf(1.0f + e);
}
__device__ __forceinline__ float ftanh(float x) {
    float e = __builtin_amdgcn_exp2f(2.88539008f * x);
    return 1.0f - 2.0f * __builtin_amdgcn_rcpf(e + 1.0f);
}
__device__ __forceinline__ uint32_t pk2h(float lo, float hi) {
    unsigned short ul = __half_as_ushort(__float2half(lo));
    unsigned short uh = __half_as_ushort(__float2half(hi));
    return ((uint32_t)uh << 16) | ul;
}

// mixed-precision FMA: acc(f32) += f16(a) * f16(b); lo/hi half selected.
// R8's exact arithmetic, kept bit-identical (absmax 4.88e-4 proven; any
// reorder of the accumulation re-rolls the fp16-envelope dice vs 1.37e-3).
#define MIX_LO(acc, a, b) asm("v_fma_mix_f32 %0, %1, %2, %0 op_sel:[0,0,0] op_sel_hi:[1,1,0]" : "+v"(acc) : "v"(a), "v"(b));
#define MIX_HI(acc, a, b) asm("v_fma_mix_f32 %0, %1, %2, %0 op_sel:[1,1,0] op_sel_hi:[1,1,0]" : "+v"(acc) : "v"(a), "v"(b));
#define PIN(a) asm volatile("" : "+v"(a));

#define FORW61(F) F(0) F(1) F(2) F(3) F(4) F(5) F(6) F(7) F(8) F(9) F(10) F(11) F(12) F(13) F(14) F(15) \
 F(16) F(17) F(18) F(19) F(20) F(21) F(22) F(23) F(24) F(25) F(26) F(27) F(28) F(29) F(30) F(31) \
 F(32) F(33) F(34) F(35) F(36) F(37) F(38) F(39) F(40) F(41) F(42) F(43) F(44) F(45) F(46) F(47) \
 F(48) F(49) F(50) F(51) F(52) F(53) F(54) F(55) F(56) F(57) F(58) F(59) F(60)
#define FOR13(F) F(0) F(1) F(2) F(3) F(4) F(5) F(6) F(7) F(8) F(9) F(10) F(11) F(12)

// 512 threads = 8 waves = 2 waves/SIMD (VGPR budget 256/thread).
// R8 skeleton + R8 math. Changes vs R8 are scheduling/layout only:
//  - region1 preloads ALL 20 h-chunks into named registers before the MIX
//    body (pays LDS latency once, not per chunk) — R8's stall source.
//  - g2w flat [g*121+j] (R10's interleave caused 8-way write conflicts).
//  - y-reduce: 3-level shfl + 16 LDS partials, summed by tid 510 in region1.
// tid 0..483  : gates2 row r=tid (region1); tid<121 also act role (region2)
// tid 484..509: LSTM1 unit l=tid-484 (region2; x-prefetch in region1)
// tid 510     : y partial-sum + store of step t-1 (region1)
__global__ __attribute__((amdgpu_flat_work_group_size(512, 512)))
__attribute__((amdgpu_waves_per_eu(2, 2)))
void lstm_seq_kernel(
    const float* __restrict__ x,
    const float* __restrict__ W_ih1, const float* __restrict__ W_hh1,
    const float* __restrict__ b_ih1, const float* __restrict__ b_hh1,
    const float* __restrict__ W_ih2, const float* __restrict__ W_hh2,
    const float* __restrict__ b_ih2, const float* __restrict__ b_hh2,
    const float* __restrict__ W_lin, const float* __restrict__ b_lin,
    const float* __restrict__ h1_0, const float* __restrict__ c1_0,
    const float* __restrict__ h2_0, const float* __restrict__ c2_0,
    float* __restrict__ out)
{
    __shared__ __align__(16) unsigned short h2f16[128];  // h2(t) fp16, pad 121..127 = 0
    __shared__ __align__(16) unsigned short h1f16[32];   // h1(t) fp16, pad 26..31 = 0
    __shared__ __align__(16) float g2w[484];             // flat [g*121 + j]
    __shared__ __align__(16) float yp8[16];              // 8-lane partial sums

    const int tid = threadIdx.x;
    const bool is_g2 = (tid < 484);
    const int  l     = tid - 484;
    const bool is_l1 = ((unsigned)l < 26u);

    // ---------------- packed-f16 weight registers ----------------
#define DECW(i) uint32_t w##i = 0;
    FORW61(DECW)
#define DECU(i) uint32_t u##i = 0;
    FOR13(DECU)
#define DECK(i) uint32_t k0_##i = 0, k1_##i = 0, k2_##i = 0, k3_##i = 0;
    FOR13(DECK)
    uint32_t i0_0=0,i0_1=0,i0_2=0, i1_0=0,i1_1=0,i1_2=0;
    uint32_t i2_0=0,i2_1=0,i2_2=0, i3_0=0,i3_1=0,i3_2=0;
    float bias = 0.0f, c2 = 0.0f, wlin = 0.0f;
    float bb0=0, bb1=0, bb2=0, bb3=0, c1 = 0.0f;
    uint32_t px01 = 0, px23 = 0, px4r = 0;

    if (is_g2) {
        const float* wp = W_hh2 + tid * H2;
#define PKW(i) w##i = pk2h(wp[2*(i)], wp[2*(i)+1]);
        PKW(0) PKW(1) PKW(2) PKW(3) PKW(4) PKW(5) PKW(6) PKW(7) PKW(8) PKW(9)
        PKW(10) PKW(11) PKW(12) PKW(13) PKW(14) PKW(15) PKW(16) PKW(17) PKW(18) PKW(19)
        PKW(20) PKW(21) PKW(22) PKW(23) PKW(24) PKW(25) PKW(26) PKW(27) PKW(28) PKW(29)
        PKW(30) PKW(31) PKW(32) PKW(33) PKW(34) PKW(35) PKW(36) PKW(37) PKW(38) PKW(39)
        PKW(40) PKW(41) PKW(42) PKW(43) PKW(44) PKW(45) PKW(46) PKW(47) PKW(48) PKW(49)
        PKW(50) PKW(51) PKW(52) PKW(53) PKW(54) PKW(55) PKW(56) PKW(57) PKW(58) PKW(59)
        w60 = pk2h(wp[120], 0.0f);
        const float* up = W_ih2 + tid * H1;
#define PKU(i) u##i = pk2h(up[2*(i)], up[2*(i)+1]);
        FOR13(PKU)
        bias = b_ih2[tid] + b_hh2[tid];
#define PINW(i) PIN(w##i)
        FORW61(PINW)
#define PINU(i) PIN(u##i)
        FOR13(PINU)
        PIN(bias)
    } else if (is_l1) {
        const float* p0 = W_hh1 + (0 * 26 + l) * H1;
        const float* p1 = W_hh1 + (1 * 26 + l) * H1;
        const float* p2 = W_hh1 + (2 * 26 + l) * H1;
        const float* p3 = W_hh1 + (3 * 26 + l) * H1;
#define PKK(i) k0_##i = pk2h(p0[2*(i)], p0[2*(i)+1]); k1_##i = pk2h(p1[2*(i)], p1[2*(i)+1]); \
               k2_##i = pk2h(p2[2*(i)], p2[2*(i)+1]); k3_##i = pk2h(p3[2*(i)], p3[2*(i)+1]);
        FOR13(PKK)
        const float* q0 = W_ih1 + (0 * 26 + l) * IN_DIM;
        const float* q1 = W_ih1 + (1 * 26 + l) * IN_DIM;
        const float* q2 = W_ih1 + (2 * 26 + l) * IN_DIM;
        const float* q3 = W_ih1 + (3 * 26 + l) * IN_DIM;
        i0_0 = pk2h(q0[0], q0[1]); i0_1 = pk2h(q0[2], q0[3]); i0_2 = pk2h(q0[4], 0.0f);
        i1_0 = pk2h(q1[0], q1[1]); i1_1 = pk2h(q1[2], q1[3]); i1_2 = pk2h(q1[4], 0.0f);
        i2_0 = pk2h(q2[0], q2[1]); i2_1 = pk2h(q2[2], q2[3]); i2_2 = pk2h(q2[4], 0.0f);
        i3_0 = pk2h(q3[0], q3[1]); i3_1 = pk2h(q3[2], q3[3]); i3_2 = pk2h(q3[4], 0.0f);
        bb0 = b_ih1[l]      + b_hh1[l];
        bb1 = b_ih1[26 + l] + b_hh1[26 + l];
        bb2 = b_ih1[52 + l] + b_hh1[52 + l];
        bb3 = b_ih1[78 + l] + b_hh1[78 + l];
        c1  = c1_0[l];
        px01 = pk2h(x[0], x[1]); px23 = pk2h(x[2], x[3]); px4r = pk2h(x[4], 0.0f);
#define PINK(i) PIN(k0_##i) PIN(k1_##i) PIN(k2_##i) PIN(k3_##i)
        FOR13(PINK)
        PIN(i0_0) PIN(i0_1) PIN(i0_2) PIN(i1_0) PIN(i1_1) PIN(i1_2)
        PIN(i2_0) PIN(i2_1) PIN(i2_2) PIN(i3_0) PIN(i3_1) PIN(i3_2)
        PIN(bb0) PIN(bb1) PIN(bb2) PIN(bb3)
    }
    if (tid < H2) { c2 = c2_0[tid]; wlin = W_lin[tid]; PIN(c2) PIN(wlin) }
    const float blin = b_lin[0];

    if (tid < 32)  h1f16[tid] = (tid < H1) ? __half_as_ushort(__float2half(h1_0[tid])) : (unsigned short)0;
    if (tid >= 32 && tid < 160) {
        int j = tid - 32;
        h2f16[j] = (j < H2) ? __half_as_ushort(__float2half(h2_0[j])) : (unsigned short)0;
    }
    __syncthreads();

    // LSTM1 step macro (R8-identical): gates from h1f16 broadcast + packed x
#define L1_STEP() { \
        const uint4* Hc = (const uint4*)h1f16; \
        uint4 hc0 = Hc[0], hc1 = Hc[1], hc2 = Hc[2], hc3 = Hc[3]; \
        float A0 = bb0, A1 = bb1, A2 = bb2, A3 = bb3; \
        MIX_LO(A0, i0_0, px01) MIX_HI(A0, i0_0, px01) MIX_LO(A0, i0_1, px23) MIX_HI(A0, i0_1, px23) MIX_LO(A0, i0_2, px4r) \
        MIX_LO(A1, i1_0, px01) MIX_HI(A1, i1_0, px01) MIX_LO(A1, i1_1, px23) MIX_HI(A1, i1_1, px23) MIX_LO(A1, i1_2, px4r) \
        MIX_LO(A2, i2_0, px01) MIX_HI(A2, i2_0, px01) MIX_LO(A2, i2_1, px23) MIX_HI(A2, i2_1, px23) MIX_LO(A2, i2_2, px4r) \
        MIX_LO(A3, i3_0, px01) MIX_HI(A3, i3_0, px01) MIX_LO(A3, i3_1, px23) MIX_HI(A3, i3_1, px23) MIX_LO(A3, i3_2, px4r) \
        GATE(A0, k0_) GATE(A1, k1_) GATE(A2, k2_) GATE(A3, k3_) \
        c1 = fsig(A1) * c1 + fsig(A0) * ftanh(A2); \
        h1f16[l] = __half_as_ushort(__float2half(fsig(A3) * ftanh(c1))); }
#define GATE(A, K) \
        MIX_LO(A, K##0, hc0.x) MIX_HI(A, K##0, hc0.x) MIX_LO(A, K##1, hc0.y) MIX_HI(A, K##1, hc0.y) \
        MIX_LO(A, K##2, hc0.z) MIX_HI(A, K##2, hc0.z) MIX_LO(A, K##3, hc0.w) MIX_HI(A, K##3, hc0.w) \
        MIX_LO(A, K##4, hc1.x) MIX_HI(A, K##4, hc1.x) MIX_LO(A, K##5, hc1.y) MIX_HI(A, K##5, hc1.y) \
        MIX_LO(A, K##6, hc1.z) MIX_HI(A, K##6, hc1.z) MIX_LO(A, K##7, hc1.w) MIX_HI(A, K##7, hc1.w) \
        MIX_LO(A, K##8, hc2.x) MIX_HI(A, K##8, hc2.x) MIX_LO(A, K##9, hc2.y) MIX_HI(A, K##9, hc2.y) \
        MIX_LO(A, K##10, hc2.z) MIX_HI(A, K##10, hc2.z) MIX_LO(A, K##11, hc2.w) MIX_HI(A, K##11, hc2.w) \
        MIX_LO(A, K##12, hc3.x) MIX_HI(A, K##12, hc3.x)

    // prologue: h1(0) from x(0), h1_0, c1_0
    if (is_l1) { L1_STEP() }
    __syncthreads();

    for (int t = 0; t < T_STEPS; ++t) {
        // -------- Region 1: gates2 = W_hh2@h2(t-1) + W_ih2@h1(t) + b --------
        if (is_g2) {
            const uint4* Hh = (const uint4*)h2f16;
            const uint4* Hl = (const uint4*)h1f16;
            // full preload: 20 uniform chunks issued back-to-back (latency
            // paid once; VGPR budget 256 at 2 waves/EU absorbs the 80 regs)
            uint4 ha0 = Hh[0],  ha1 = Hh[1],  ha2 = Hh[2],  ha3 = Hh[3];
            uint4 ha4 = Hh[4],  ha5 = Hh[5],  ha6 = Hh[6],  ha7 = Hh[7];
            uint4 ha8 = Hh[8],  ha9 = Hh[9],  ha10 = Hh[10], ha11 = Hh[11];
            uint4 ha12 = Hh[12], ha13 = Hh[13], ha14 = Hh[14], ha15 = Hh[15];
            uint4 hb0 = Hl[0], hb1 = Hl[1], hb2 = Hl[2], hb3 = Hl[3];
            float a0 = bias, a1 = 0.0f, a2 = 0.0f, a3 = 0.0f;
#define CH(HV, WA, WB, WC, WD) \
            MIX_LO(a0, WA, HV.x) MIX_HI(a1, WA, HV.x) MIX_LO(a2, WB, HV.y) MIX_HI(a3, WB, HV.y) \
            MIX_LO(a0, WC, HV.z) MIX_HI(a1, WC, HV.z) MIX_LO(a2, WD, HV.w) MIX_HI(a3, WD, HV.w)
            CH(ha0,  w0,  w1,  w2,  w3)
            CH(ha1,  w4,  w5,  w6,  w7)
            CH(ha2,  w8,  w9,  w10, w11)
            CH(ha3,  w12, w13, w14, w15)
            CH(ha4,  w16, w17, w18, w19)
            CH(ha5,  w20, w21, w22, w23)
            CH(ha6,  w24, w25, w26, w27)
            CH(ha7,  w28, w29, w30, w31)
            CH(ha8,  w32, w33, w34, w35)
            CH(ha9,  w36, w37, w38, w39)
            CH(ha10, w40, w41, w42, w43)
            CH(ha11, w44, w45, w46, w47)
            CH(ha12, w48, w49, w50, w51)
            CH(ha13, w52, w53, w54, w55)
            CH(ha14, w56, w57, w58, w59)
            MIX_LO(a0, w60, ha15.x) MIX_HI(a1, w60, ha15.x)
            CH(hb0,  u0,  u1,  u2,  u3)
            CH(hb1,  u4,  u5,  u6,  u7)
            CH(hb2,  u8,  u9,  u10, u11)
            MIX_LO(a0, u12, hb3.x) MIX_HI(a1, u12, hb3.x)
            g2w[tid] = (a0 + a1) + (a2 + a3);
        } else if (is_l1) {
            int tn = t + 1; if (tn >= T_STEPS) tn = T_STEPS - 1;
            const float* xp = x + tn * IN_DIM;
            px01 = pk2h(xp[0], xp[1]); px23 = pk2h(xp[2], xp[3]); px4r = pk2h(xp[4], 0.0f);
        } else if (tid == 510) {
            if (t > 0) {
                const float4* Y4 = (const float4*)yp8;
                float4 y0 = Y4[0], y1 = Y4[1], y2 = Y4[2], y3 = Y4[3];
                float s = ((y0.x + y0.y) + (y0.z + y0.w))
                        + ((y1.x + y1.y) + (y1.z + y1.w))
                        + ((y2.x + y2.y) + (y2.z + y2.w))
                        + ((y3.x + y3.y) + (y3.z + y3.w));
                out[t - 1] = s + blin;
            }
        }
        __syncthreads();   // B2: gates2 visible

        // -------- Region 2: h2/c2 act + y partials  ||  LSTM1 -> h1(t+1) --------
        if (tid < 128) {
            float p = 0.0f;
            if (tid < H2) {
                float gi = g2w[tid];
                float gf = g2w[121 + tid];
                float gg = g2w[242 + tid];
                float go = g2w[363 + tid];
                c2 = fsig(gf) * c2 + fsig(gi) * ftanh(gg);
                float h2n = fsig(go) * ftanh(c2);
                h2f16[tid] = __half_as_ushort(__float2half(h2n));
                p = h2n * wlin;
            }
            // 3-level butterfly within 8-lane groups; 16 partials to LDS
            p += __shfl_xor(p, 1);
            p += __shfl_xor(p, 2);
            p += __shfl_xor(p, 4);
            if ((tid & 7) == 0) yp8[tid >> 3] = p;
        } else if (is_l1) {
            L1_STEP()
        }
        __syncthreads();   // B3: h2(t), yp8, h1(t+1) visible
    }

    if (tid == 510) {
        const float4* Y4 = (const float4*)yp8;
        float4 y0 = Y4[0], y1 = Y4[1], y2 = Y4[2], y3 = Y4[3];
        float s = ((y0.x + y0.y) + (y0.z + y0.w))
                + ((y1.x + y1.y) + (y1.z + y1.w))
                + ((y2.x + y2.y) + (y2.z + y2.w))
                + ((y3.x + y3.y) + (y3.z + y3.w));
        out[T_STEPS - 1] = s + blin;
    }
}

extern "C" void kernel_launch(void* const* d_in, const int* in_sizes, int n_in,
                              void* d_out, int out_size, void* d_ws, size_t ws_size,
                              hipStream_t stream) {
    const float* x     = (const float*)d_in[0];
    const float* W_ih1 = (const float*)d_in[1];
    const float* W_hh1 = (const float*)d_in[2];
    const float* b_ih1 = (const float*)d_in[3];
    const float* b_hh1 = (const float*)d_in[4];
    const float* W_ih2 = (const float*)d_in[5];
    const float* W_hh2 = (const float*)d_in[6];
    const float* b_ih2 = (const float*)d_in[7];
    const float* b_hh2 = (const float*)d_in[8];
    const float* W_lin = (const float*)d_in[9];
    const float* b_lin = (const float*)d_in[10];
    const float* h1_0  = (const float*)d_in[11];
    const float* c1_0  = (const float*)d_in[12];
    const float* h2_0  = (const float*)d_in[13];
    const float* c2_0  = (const float*)d_in[14];
    float* out = (float*)d_out;

    hipLaunchKernelGGL(lstm_seq_kernel, dim3(1), dim3(512), 0, stream,
                       x, W_ih1, W_hh1, b_ih1, b_hh1,
                       W_ih2, W_hh2, b_ih2, b_hh2,
                       W_lin, b_lin, h1_0, c1_0, h2_0, c2_0, out);
}